// Round 1
// baseline (445.430 us; speedup 1.0000x reference)
//
#include <hip/hip_runtime.h>
#include <hip/hip_cooperative_groups.h>

namespace cg = cooperative_groups;

#define MM 1024
#define NN 2048
#define RCAP 64              // row capacity (mean deg 22.5, +9 sigma)
#define ROWS_PER_BLOCK 2
#define THREADS 512
#define NBLOCKS (MM / ROWS_PER_BLOCK)
#define INFF __builtin_inff()

typedef unsigned short u16;

__device__ __forceinline__ float signf(float x) {
    return (x > 0.0f) ? 1.0f : ((x < 0.0f) ? -1.0f : 0.0f);  // jnp.sign
}

// merge (om,os) min/2nd-min pair into (mn,sub)
__device__ __forceinline__ void mmerge(float& mn, float& sub, float om, float os) {
    float hi = fmaxf(mn, om);
    mn = fminf(mn, om);
    sub = fminf(fminf(sub, os), hi);
}

// One persistent cooperative kernel: build row lists once, then 5 BP iterations
// separated by grid syncs. Check-node stats are computed row-parallel (16 lanes
// per (b,m)) and the check->variable messages are scattered with atomicAdd into
// the next soft buffer -- no stats array, no CSC, no per-phase kernel launches.
// Buffer rotation (nxt must be pre-initialized to soft_in before scatters):
//   it1: cur=soft_in nxt=n1 ini=n2   (n1 init in prologue)
//   it2: cur=n1      nxt=n2 ini=n3
//   it3: cur=n2      nxt=n3 ini=n1   (n1 last read in it2 -> safe to overwrite)
//   it4: cur=n3      nxt=n1 ini=out
//   it5: cur=n1      nxt=out
__global__ __launch_bounds__(THREADS)
void bp_fused(const int4* __restrict__ H4, const float* __restrict__ soft_in,
              const float* __restrict__ wptr,
              float* __restrict__ n1, float* __restrict__ n2,
              float* __restrict__ n3, float* __restrict__ out)
{
    __shared__ u16 s_cols[ROWS_PER_BLOCK][RCAP];
    __shared__ int s_cnt[ROWS_PER_BLOCK];

    const int t  = threadIdx.x;
    const int lr = t >> 8;               // local row 0/1 (256 threads each)
    const int m  = blockIdx.x * ROWS_PER_BLOCK + lr;
    const int b  = (t >> 4) & 15;        // batch element
    const int k  = t & 15;               // lane within 16-lane edge group (aligned)

    if (t < ROWS_PER_BLOCK) s_cnt[t] = 0;
    __syncthreads();

    // ---- build this block's row edge lists (block-local; CSC never needed) ----
    {
        const int4* hrow = H4 + m * (NN / 4);
        const int tt = t & 255;
#pragma unroll
        for (int h = 0; h < 2; ++h) {
            const int i = tt + h * 256;          // int4 index within the row
            int4 hv4 = hrow[i];
            int hv[4] = {hv4.x, hv4.y, hv4.z, hv4.w};
#pragma unroll
            for (int kk = 0; kk < 4; ++kk) {
                if (hv[kk]) {
                    int j = atomicAdd(&s_cnt[lr], 1);   // LDS atomic
                    if (j < RCAP) s_cols[lr][j] = (u16)(i * 4 + kk);
                }
            }
        }
    }

    // init n1 = soft_in for this block's 64-float slice (coalesced float4)
    {
        const float4* src = (const float4*)soft_in;
        float4* dst = (float4*)n1;
        if (t < 16) dst[blockIdx.x * 16 + t] = src[blockIdx.x * 16 + t];
    }
    __syncthreads();

    const int deg = min(s_cnt[lr], RCAP);
    const float norm = log1pf(expf(wptr[0]));   // softplus(w)

    // hoist iteration-invariant edge indices into registers (static unroll,
    // no runtime indexing -> stays in VGPRs, rule #20)
    int  cc[4];
    bool act[4];
#pragma unroll
    for (int s = 0; s < 4; ++s) {
        int j = k + (s << 4);
        act[s] = (j < deg);
        cc[s] = act[s] ? (int)s_cols[lr][j] : 0;   // 0 is always a valid column
    }

    const int bOff = b * NN;
    cg::grid_group grid = cg::this_grid();
    grid.sync();   // n1 init + (nothing else cross-block) visible

    auto iter = [&](const float* __restrict__ cur, float* __restrict__ nxt,
                    float* __restrict__ ini) {
        const float* sp = cur + bOff;
        float xv[4];
        float sgn = 1.0f, mn = INFF, sub = INFF;
#pragma unroll
        for (int s = 0; s < 4; ++s) {
            float x0 = sp[cc[s]];                // always in-bounds
            float x  = act[s] ? x0 : INFF;       // neutral: sign=+1, |x|=inf
            xv[s] = x;
            sgn *= signf(x);
            float a = fabsf(x);
            if (a < mn) { sub = mn; mn = a; }
            else if (a < sub) sub = a;
        }
#pragma unroll
        for (int off = 1; off < 16; off <<= 1) { // 16-lane groups are wave-aligned
            sgn *= __shfl_xor(sgn, off, 16);
            float om = __shfl_xor(mn, off, 16);
            float os = __shfl_xor(sub, off, 16);
            mmerge(mn, sub, om, os);
        }
        sgn *= norm;
        // overlap: init the buffer used two iterations ahead (owning block slice)
        if (ini) {
            const float4* src = (const float4*)soft_in;
            float4* dst = (float4*)ini;
            if (t < 16) dst[blockIdx.x * 16 + t] = src[blockIdx.x * 16 + t];
        }
        // scatter extrinsic messages; x values already in registers
        float* np = nxt + bOff;
#pragma unroll
        for (int s = 0; s < 4; ++s) {
            if (act[s]) {
                float x = xv[s];
                float cvv = sgn * signf(x) * ((fabsf(x) > mn) ? mn : sub);
                atomicAdd(&np[cc[s]], cvv);
            }
        }
    };

    iter(soft_in, n1, n2);  grid.sync();
    iter(n1,      n2, n3);  grid.sync();
    iter(n2,      n3, n1);  grid.sync();
    iter(n3,      n1, out); grid.sync();
    iter(n1,      out, nullptr);
}

extern "C" void kernel_launch(void* const* d_in, const int* in_sizes, int n_in,
                              void* d_out, int out_size, void* d_ws, size_t ws_size,
                              hipStream_t stream)
{
    const float* soft_in = (const float*)d_in[0];
    const int4*  H4      = (const int4*)d_in[1];
    // d_in[2] = labels (unused by forward reference)
    const float* w       = (const float*)d_in[3];
    float* out = (float*)d_out;

    char* ws = (char*)d_ws;
    float* n1 = (float*)(ws);             //      0, 128 KB
    float* n2 = (float*)(ws + 131072);    // 131072, 128 KB
    float* n3 = (float*)(ws + 262144);    // 262144, 128 KB

    void* args[7] = { (void*)&H4, (void*)&soft_in, (void*)&w,
                      (void*)&n1, (void*)&n2, (void*)&n3, (void*)&out };
    hipLaunchCooperativeKernel((void*)bp_fused, dim3(NBLOCKS), dim3(THREADS),
                               args, 0, stream);
}

// Round 2
// 153.221 us; speedup vs baseline: 2.9071x; 2.9071x over previous
//
#include <hip/hip_runtime.h>

#define BB 16
#define MM 1024
#define NN 2048
#define RCAP 64   // row capacity (mean deg 22.5, sigma ~4.7; 64 = +9 sigma)
#define CCAP 48   // col capacity c>=2 (mean 10.2, sigma ~3.2; 48 = +11 sigma)
#define INFF __builtin_inff()

typedef unsigned short u16;

__device__ __forceinline__ float signf(float x) {
    return (x > 0.0f) ? 1.0f : ((x < 0.0f) ? -1.0f : 0.0f);  // jnp.sign
}

// Build CSR + CSC once. Block per row. CSR order is irrelevant (min/2nd-min and
// sign-product are order-independent). CSC order from global atomics is
// nondeterministic but only permutes a ~10-term float sum (baseline-proven OK).
__global__ __launch_bounds__(256)
void build_lists(const int4* __restrict__ H4,
                 int* __restrict__ row_deg, u16* __restrict__ row_cols,
                 int* __restrict__ col_deg, u16* __restrict__ col_rows) {
    __shared__ u16 s_cols[RCAP];
    __shared__ int s_cnt;
    const int m = blockIdx.x, t = threadIdx.x;
    if (t == 0) s_cnt = 0;
    __syncthreads();
    const int4* hrow = H4 + m * (NN / 4);
#pragma unroll
    for (int half = 0; half < 2; ++half) {
        int i = t + half * 256;              // int4 index within the row
        int4 h = hrow[i];
        int hv[4] = {h.x, h.y, h.z, h.w};
#pragma unroll
        for (int k = 0; k < 4; ++k) {
            if (hv[k]) {
                int c = i * 4 + k;
                int j = atomicAdd(&s_cnt, 1);             // LDS atomic
                if (j < RCAP) s_cols[j] = (u16)c;
                if (c >= 2) {                              // cols 0,1 analytic
                    int j2 = atomicAdd(&col_deg[c], 1);
                    if (j2 < CCAP) col_rows[c * CCAP + j2] = (u16)m;
                }
            }
        }
    }
    __syncthreads();
    if (t == 0) row_deg[m] = min(s_cnt, RCAP);
    if (t < 8) ((int4*)(row_cols + m * RCAP))[t] = ((const int4*)s_cols)[t];
}

// Gather check->variable contributions for one column from LDS stats.
// Indices in statically-unrolled int4 batches (stay in VGPRs).
__device__ __forceinline__ float col_acc(const int4 (&ci)[6], int deg, float x,
                                         const float4* __restrict__ st) {
    float a = fabsf(x), sx = signf(x), acc = 0.0f;
#pragma unroll
    for (int jb = 0; jb < CCAP; jb += 8) {
        if (jb < deg) {
            const u16* q = (const u16*)&ci[jb >> 3];
#pragma unroll
            for (int k = 0; k < 8; ++k) {
                float4 s = st[q[k] & (MM - 1)];
                float cv = s.x * ((a > s.y) ? s.y : s.z) * sx;
                acc += (jb + k < deg) ? cv : 0.0f;
            }
        }
    }
    return acc;
}

// One block per batch element; soft + stats LDS-resident; 5 iterations inside
// the block. No global atomics, no grid syncs, no inter-block traffic.
__global__ __launch_bounds__(1024)
void bp_solve(const float* __restrict__ soft_in, const float* __restrict__ wptr,
              const int* __restrict__ row_deg, const u16* __restrict__ row_cols,
              const int* __restrict__ col_deg, const u16* __restrict__ col_rows,
              float* __restrict__ out) {
    __shared__ float  s_in[NN];        //  8 KB  channel LLRs
    __shared__ float  s_buf[2][NN];    // 16 KB  soft double-buffer
    __shared__ float4 s_stats[MM];     // 16 KB  (norm*sgn, mn, sub, -)
    __shared__ float  s_red[2][16];    // heavy-col wave partials

    const int b = blockIdx.x, t = threadIdx.x;
    {
        const float4* sp = (const float4*)(soft_in + b * NN);
        float4* di = (float4*)s_in;
        float4* d0 = (float4*)s_buf[0];
        if (t < NN / 4) { float4 v = sp[t]; di[t] = v; d0[t] = v; }
    }
    const float norm = log1pf(expf(wptr[0]));   // softplus(w)

    // ---- hoist iteration-invariant edge lists into registers ----
    const int m = t;                            // phase-A row
    const int rdeg = row_deg[m];
    int4 ri[8];
    {
        const int4* p = (const int4*)(row_cols + m * RCAP);
#pragma unroll
        for (int j = 0; j < 8; ++j) ri[j] = p[j];
    }
    const int n0 = t, n1 = t + 1024;            // phase-B columns
    const int cdeg0 = (n0 >= 2) ? min(col_deg[n0], CCAP) : 0;
    const int cdeg1 = min(col_deg[n1], CCAP);
    int4 ci0[6], ci1[6];
    {
        const int4* p0 = (const int4*)(col_rows + n0 * CCAP);
        const int4* p1 = (const int4*)(col_rows + n1 * CCAP);
#pragma unroll
        for (int j = 0; j < 6; ++j) { ci0[j] = p0[j]; ci1[j] = p1[j]; }
    }
    __syncthreads();

#pragma unroll 1
    for (int it = 0; it < 5; ++it) {
        float* cur = s_buf[it & 1];
        float* nxt = s_buf[(it + 1) & 1];

        // ---- phase A: check-node stats, thread = row ----
        float sgn = 1.0f, mn = INFF, sub = INFF;
#pragma unroll
        for (int jb = 0; jb < RCAP; jb += 8) {
            if (jb < rdeg) {
                const u16* q = (const u16*)&ri[jb >> 3];
#pragma unroll
                for (int k = 0; k < 8; ++k) {
                    float x = cur[q[k] & (NN - 1)];
                    x = (jb + k < rdeg) ? x : INFF;   // neutral: sign +1, |x| inf
                    sgn *= signf(x);
                    float a = fabsf(x);
                    if (a < mn) { sub = mn; mn = a; }
                    else if (a < sub) sub = a;
                }
            }
        }
        s_stats[m] = make_float4(norm * sgn, mn, sub, 0.0f);
        __syncthreads();

        // ---- phase B: variable-node update, thread = 2 columns ----
        if (n0 >= 2) nxt[n0] = s_in[n0] + col_acc(ci0, cdeg0, cur[n0], s_stats);
        nxt[n1] = s_in[n1] + col_acc(ci1, cdeg1, cur[n1], s_stats);

        // heavy cols 0,1: every row connects; block-wide reduction
        {
            float x0 = cur[0], x1 = cur[1];
            float a0 = fabsf(x0), sx0 = signf(x0);
            float a1 = fabsf(x1), sx1 = signf(x1);
            float4 s = s_stats[t];
            float acc0 = s.x * ((a0 > s.y) ? s.y : s.z) * sx0;
            float acc1 = s.x * ((a1 > s.y) ? s.y : s.z) * sx1;
#pragma unroll
            for (int off = 1; off < 64; off <<= 1) {
                acc0 += __shfl_xor(acc0, off);
                acc1 += __shfl_xor(acc1, off);
            }
            if ((t & 63) == 0) { s_red[0][t >> 6] = acc0; s_red[1][t >> 6] = acc1; }
        }
        __syncthreads();
        if (t < 2) {
            float acc = 0.0f;
#pragma unroll
            for (int wv = 0; wv < 16; ++wv) acc += s_red[t][wv];
            nxt[t] = s_in[t] + acc;
        }
        __syncthreads();
    }

    // 5 iterations end with result in s_buf[1]
    {
        const float4* sres = (const float4*)s_buf[1];
        float4* dst = (float4*)(out + b * NN);
        if (t < NN / 4) dst[t] = sres[t];
    }
}

extern "C" void kernel_launch(void* const* d_in, const int* in_sizes, int n_in,
                              void* d_out, int out_size, void* d_ws, size_t ws_size,
                              hipStream_t stream)
{
    const float* soft_in = (const float*)d_in[0];
    const int4*  H4      = (const int4*)d_in[1];
    // d_in[2] = labels (unused by forward reference)
    const float* w       = (const float*)d_in[3];
    float* out = (float*)d_out;

    char* ws = (char*)d_ws;
    int* col_deg  = (int*)ws;                     //      0,   8 KB (memset)
    int* row_deg  = (int*)(ws + 8192);            //   8192,   4 KB
    u16* row_cols = (u16*)(ws + 12288);           //  12288, 128 KB
    u16* col_rows = (u16*)(ws + 143360);          // 143360, 192 KB

    hipMemsetAsync(col_deg, 0, NN * sizeof(int), stream);
    build_lists<<<MM, 256, 0, stream>>>(H4, row_deg, row_cols, col_deg, col_rows);
    bp_solve<<<BB, 1024, 0, stream>>>(soft_in, w, row_deg, row_cols,
                                      col_deg, col_rows, out);
}